// Round 1
// baseline (544.616 us; speedup 1.0000x reference)
//
#include <hip/hip_runtime.h>
#include <math.h>

// JCPOT Sinkhorn: C = pairwise dist, K = exp(-C/8), 10 Sinkhorn iters, coupling + loss.
// d_out layout: [0]=loss, [1 .. 16M]=coupling, [1+16M .. 1+32M]=C
// K is staged in the coupling slot of d_out (dead until final pass) -> ws stays tiny (~80KB).

#define N_S 4096
#define N_T 4096
#define DIM 512
#define STAB 1e-8f

typedef _Float16 f16x4 __attribute__((ext_vector_type(4)));
typedef _Float16 f16x8 __attribute__((ext_vector_type(8)));
typedef float f32x4v __attribute__((ext_vector_type(4)));

// ---------- row squared norms of S and T (wave per row) ----------
__global__ __launch_bounds__(256) void k_norms(const float4* __restrict__ S4,
                                               const float4* __restrict__ T4,
                                               float* __restrict__ ns, float* __restrict__ nt) {
    int t = threadIdx.x;
    int lane = t & 63, wave = t >> 6;
    int wid = blockIdx.x * 4 + wave;          // 0..8191
    const float4* src; float* dst; int row;
    if (wid < N_S) { src = S4; dst = ns; row = wid; }
    else           { src = T4; dst = nt; row = wid - N_S; }
    float acc = 0.f;
#pragma unroll
    for (int c = 0; c < 2; ++c) {
        float4 x = src[row * 128 + c * 64 + lane];
        acc += x.x*x.x + x.y*x.y + x.z*x.z + x.w*x.w;
    }
#pragma unroll
    for (int m = 32; m; m >>= 1) acc += __shfl_xor(acc, m);
    if (lane == 0) dst[row] = acc;
}

// ---------- init v=1, vacc=0, loss=0 ----------
__global__ void k_init(float* v, float* vacc, double* lossd) {
    int g = blockIdx.x * 256 + threadIdx.x;
    if (g < N_T) { v[g] = 1.0f; vacc[g] = 0.0f; }
    if (g == 0) *lossd = 0.0;
}

// ---------- GEMM (f16 MFMA) + epilogue: C = sqrt(max(ns+nt-2*dot,0)), K = exp(-C/8) ----------
__global__ __launch_bounds__(256) void k_gemm(const float* __restrict__ S, const float* __restrict__ T,
                                              const float* __restrict__ ns, const float* __restrict__ nt,
                                              float* __restrict__ outK, float* __restrict__ outC) {
    __shared__ _Float16 As[128 * 40];   // 128 rows x 32 k + 8 pad (bank-conflict pad)
    __shared__ _Float16 Bs[128 * 40];
    int t = threadIdx.x;
    int lane = t & 63, wave = t >> 6;
    int wr = wave >> 1, wc = wave & 1;
    int brow = blockIdx.x * 128, bcol = blockIdx.y * 128;

    f32x4v acc[4][4] = {};

    for (int kt = 0; kt < DIM; kt += 32) {
        __syncthreads();  // LDS readers of previous step done
#pragma unroll
        for (int w = 0; w < 4; ++w) {
            int e = w * 1024 + t * 4;        // flat element in 128x32 tile
            int row = e >> 5, col = e & 31;  // col multiple of 4
            float4 a = *(const float4*)(S + (size_t)(brow + row) * DIM + kt + col);
            f16x4 ah = { (_Float16)a.x, (_Float16)a.y, (_Float16)a.z, (_Float16)a.w };
            *(f16x4*)(&As[row * 40 + col]) = ah;
            float4 b = *(const float4*)(T + (size_t)(bcol + row) * DIM + kt + col);
            f16x4 bh = { (_Float16)b.x, (_Float16)b.y, (_Float16)b.z, (_Float16)b.w };
            *(f16x4*)(&Bs[row * 40 + col]) = bh;
        }
        __syncthreads();

        f16x8 af[4], bf[4];
#pragma unroll
        for (int m = 0; m < 4; ++m)
            af[m] = *(const f16x8*)(&As[(wr * 64 + m * 16 + (lane & 15)) * 40 + (lane >> 4) * 8]);
#pragma unroll
        for (int n = 0; n < 4; ++n)
            bf[n] = *(const f16x8*)(&Bs[(wc * 64 + n * 16 + (lane & 15)) * 40 + (lane >> 4) * 8]);
#pragma unroll
        for (int m = 0; m < 4; ++m)
#pragma unroll
            for (int n = 0; n < 4; ++n)
                acc[m][n] = __builtin_amdgcn_mfma_f32_16x16x32_f16(af[m], bf[n], acc[m][n], 0, 0, 0);
    }

    // epilogue: D layout col=lane&15, row=(lane>>4)*4+reg
#pragma unroll
    for (int m = 0; m < 4; ++m) {
#pragma unroll
        for (int n = 0; n < 4; ++n) {
#pragma unroll
            for (int r = 0; r < 4; ++r) {
                int i = brow + wr * 64 + m * 16 + (lane >> 4) * 4 + r;
                int j = bcol + wc * 64 + n * 16 + (lane & 15);
                float dot = acc[m][n][r];
                float sq = ns[i] + nt[j] - 2.0f * dot;
                float c = sqrtf(fmaxf(sq, 0.0f));
                float k = __expf(-c * 0.125f);
                size_t idx = (size_t)i * N_T + j;
                outC[idx] = c;
                outK[idx] = k;
            }
        }
    }
}

// ---------- row matvec: u[i] = (1/n)/(sum_j K[i][j]*v[j] + STAB), wave per row ----------
__global__ __launch_bounds__(256) void k_rowmv(const float* __restrict__ Kd,
                                               const float* __restrict__ v, float* __restrict__ u) {
    __shared__ float vl[4096];
    int t = threadIdx.x;
#pragma unroll
    for (int c = 0; c < 16; ++c) vl[c * 256 + t] = v[c * 256 + t];
    __syncthreads();
    int lane = t & 63, wave = t >> 6;
    int row = blockIdx.x * 4 + wave;
    const float* Kr = Kd + (size_t)row * N_T;
    float dot = 0.f;
#pragma unroll 8
    for (int c = 0; c < 64; ++c) {
        int j = c * 64 + lane;
        dot += Kr[j] * vl[j];
    }
#pragma unroll
    for (int m = 32; m; m >>= 1) dot += __shfl_xor(dot, m);
    if (lane == 0) u[row] = (1.0f / N_S) / (dot + STAB);
}

// ---------- col matvec partial: vacc[j] += sum over 64-row chunk of K[i][j]*u[i] ----------
__global__ __launch_bounds__(256) void k_colmv(const float* __restrict__ Kd,
                                               const float* __restrict__ u, float* __restrict__ vacc) {
    __shared__ float ul[64];
    int t = threadIdx.x;
    int rc = blockIdx.y;                       // row chunk 0..63
    if (t < 64) ul[t] = u[rc * 64 + t];
    __syncthreads();
    int j = blockIdx.x * 256 + t;              // column (coalesced across threads)
    const float* Kp = Kd + (size_t)(rc * 64) * N_T + j;
    float acc = 0.f;
#pragma unroll 8
    for (int r = 0; r < 64; ++r) acc += Kp[(size_t)r * N_T] * ul[r];
    atomicAdd(&vacc[j], acc);
}

// ---------- v finalize + reset accumulator ----------
__global__ void k_vfin(float* v, float* vacc) {
    int j = blockIdx.x * 256 + threadIdx.x;
    v[j] = (1.0f / N_T) / (vacc[j] + STAB);
    vacc[j] = 0.f;
}

// ---------- coupling = u*K*v in place over K; fused loss reduction ----------
__global__ __launch_bounds__(256) void k_final(float* __restrict__ Kd, const float* __restrict__ Cd,
                                               const float* __restrict__ u, const float* __restrict__ v,
                                               double* __restrict__ lossd) {
    int t = threadIdx.x;
    int row = blockIdx.x;
    float ui = u[row];
    float lacc = 0.f;
#pragma unroll 4
    for (int c = 0; c < 16; ++c) {
        int j = c * 256 + t;
        size_t idx = (size_t)row * N_T + j;
        float w = ui * Kd[idx] * v[j];
        Kd[idx] = w;                 // coupling overwrites K (each element read once, same thread)
        lacc += w * Cd[idx];
    }
#pragma unroll
    for (int m = 32; m; m >>= 1) lacc += __shfl_xor(lacc, m);
    __shared__ float wsum[4];
    int lane = t & 63, wave = t >> 6;
    if (lane == 0) wsum[wave] = lacc;
    __syncthreads();
    if (t == 0) {
        float s = wsum[0] + wsum[1] + wsum[2] + wsum[3];
        atomicAdd(lossd, (double)s);
    }
}

__global__ void k_loss(const double* __restrict__ lossd, float* __restrict__ out0) {
    *out0 = (float)(*lossd / ((double)N_S * (double)N_T));
}

extern "C" void kernel_launch(void* const* d_in, const int* in_sizes, int n_in,
                              void* d_out, int out_size, void* d_ws, size_t ws_size,
                              hipStream_t stream) {
    const float* S = (const float*)d_in[0];
    const float* T = (const float*)d_in[1];
    float* out = (float*)d_out;
    float* outK = out + 1;                              // coupling slot, holds K until final pass
    float* outC = out + 1 + (size_t)N_S * N_T;

    float* ws   = (float*)d_ws;                         // needs ~80KB
    float* ns   = ws;                                   // 4096
    float* nt   = ws + 4096;                            // 4096
    float* u    = ws + 8192;                            // 4096
    float* v    = ws + 12288;                           // 4096
    float* vacc = ws + 16384;                           // 4096
    double* lossd = (double*)(ws + 20480);              // 8B, 8-aligned

    k_norms<<<2048, 256, 0, stream>>>((const float4*)S, (const float4*)T, ns, nt);
    k_init<<<16, 256, 0, stream>>>(v, vacc, lossd);
    k_gemm<<<dim3(32, 32), 256, 0, stream>>>(S, T, ns, nt, outK, outC);
    for (int it = 0; it < 10; ++it) {
        k_rowmv<<<1024, 256, 0, stream>>>(outK, v, u);
        k_colmv<<<dim3(16, 64), 256, 0, stream>>>(outK, u, vacc);
        k_vfin<<<16, 256, 0, stream>>>(v, vacc);
    }
    k_final<<<4096, 256, 0, stream>>>(outK, outC, u, v, lossd);
    k_loss<<<1, 1, 0, stream>>>(lossd, out);
}

// Round 2
// 389.789 us; speedup vs baseline: 1.3972x; 1.3972x over previous
//
#include <hip/hip_runtime.h>
#include <math.h>

// JCPOT Sinkhorn. d_out: [0]=loss, [1..16M]=coupling, [1+16M..]=C.
// Fast path (ws >= ~42MB): K kept ONLY as fp16 in ws; fused Sinkhorn kernel reads K once/iter.
// Fallback path (small ws): round-1 proven flow with fp32 K staged in the coupling slot.

#define N_S 4096
#define N_T 4096
#define DIM 512
#define STAB 1e-8f

typedef _Float16 f16x2 __attribute__((ext_vector_type(2)));
typedef _Float16 f16x4 __attribute__((ext_vector_type(4)));
typedef _Float16 f16x8 __attribute__((ext_vector_type(8)));
typedef float f32x4v __attribute__((ext_vector_type(4)));

// ---------- row squared norms ----------
__global__ __launch_bounds__(256) void k_norms(const float4* __restrict__ S4,
                                               const float4* __restrict__ T4,
                                               float* __restrict__ ns, float* __restrict__ nt) {
    int t = threadIdx.x;
    int lane = t & 63, wave = t >> 6;
    int wid = blockIdx.x * 4 + wave;
    const float4* src; float* dst; int row;
    if (wid < N_S) { src = S4; dst = ns; row = wid; }
    else           { src = T4; dst = nt; row = wid - N_S; }
    float acc = 0.f;
#pragma unroll
    for (int c = 0; c < 2; ++c) {
        float4 x = src[row * 128 + c * 64 + lane];
        acc += x.x*x.x + x.y*x.y + x.z*x.z + x.w*x.w;
    }
#pragma unroll
    for (int m = 32; m; m >>= 1) acc += __shfl_xor(acc, m);
    if (lane == 0) dst[row] = acc;
}

__global__ void k_init(float* v, float* vacc, double* lossd) {
    int g = blockIdx.x * 256 + threadIdx.x;
    if (g < N_T) { v[g] = 1.0f; vacc[g] = 0.0f; }
    if (g == 0) *lossd = 0.0;
}

// ---------- GEMM (f16 MFMA): C = dist, K = exp(-C/8) as fp32 (MODE 0) or fp16 (MODE 1) ----------
template<int MODE>
__global__ __launch_bounds__(256) void k_gemm(const float* __restrict__ S, const float* __restrict__ T,
                                              const float* __restrict__ ns, const float* __restrict__ nt,
                                              float* __restrict__ outK, _Float16* __restrict__ outKh,
                                              float* __restrict__ outC) {
    __shared__ _Float16 As[128 * 40];
    __shared__ _Float16 Bs[128 * 40];
    int t = threadIdx.x;
    int lane = t & 63, wave = t >> 6;
    int wr = wave >> 1, wc = wave & 1;
    int brow = blockIdx.x * 128, bcol = blockIdx.y * 128;

    f32x4v acc[4][4] = {};

    for (int kt = 0; kt < DIM; kt += 32) {
        __syncthreads();
#pragma unroll
        for (int w = 0; w < 4; ++w) {
            int e = w * 1024 + t * 4;
            int row = e >> 5, col = e & 31;
            float4 a = *(const float4*)(S + (size_t)(brow + row) * DIM + kt + col);
            f16x4 ah = { (_Float16)a.x, (_Float16)a.y, (_Float16)a.z, (_Float16)a.w };
            *(f16x4*)(&As[row * 40 + col]) = ah;
            float4 b = *(const float4*)(T + (size_t)(bcol + row) * DIM + kt + col);
            f16x4 bh = { (_Float16)b.x, (_Float16)b.y, (_Float16)b.z, (_Float16)b.w };
            *(f16x4*)(&Bs[row * 40 + col]) = bh;
        }
        __syncthreads();

        f16x8 af[4], bf[4];
#pragma unroll
        for (int m = 0; m < 4; ++m)
            af[m] = *(const f16x8*)(&As[(wr * 64 + m * 16 + (lane & 15)) * 40 + (lane >> 4) * 8]);
#pragma unroll
        for (int n = 0; n < 4; ++n)
            bf[n] = *(const f16x8*)(&Bs[(wc * 64 + n * 16 + (lane & 15)) * 40 + (lane >> 4) * 8]);
#pragma unroll
        for (int m = 0; m < 4; ++m)
#pragma unroll
            for (int n = 0; n < 4; ++n)
                acc[m][n] = __builtin_amdgcn_mfma_f32_16x16x32_f16(af[m], bf[n], acc[m][n], 0, 0, 0);
    }

#pragma unroll
    for (int m = 0; m < 4; ++m) {
#pragma unroll
        for (int n = 0; n < 4; ++n) {
#pragma unroll
            for (int r = 0; r < 4; ++r) {
                int i = brow + wr * 64 + m * 16 + (lane >> 4) * 4 + r;
                int j = bcol + wc * 64 + n * 16 + (lane & 15);
                float dot = acc[m][n][r];
                float sq = ns[i] + nt[j] - 2.0f * dot;
                float c = sqrtf(fmaxf(sq, 0.0f));
                float k = __expf(-c * 0.125f);
                size_t idx = (size_t)i * N_T + j;
                outC[idx] = c;
                if constexpr (MODE == 0) outK[idx] = k;
                else                     outKh[idx] = (_Float16)k;
            }
        }
    }
}

// ---------- fused Sinkhorn iteration: u = a/(K v), per-block column partials for v ----------
// 512 blocks x 8 rows; 4-row LDS chunks; col partials in registers; no atomics.
__global__ __launch_bounds__(256) void k_sink(const _Float16* __restrict__ Kh,
                                              const float* __restrict__ v,
                                              float* __restrict__ u_out,
                                              float* __restrict__ part) {
    __shared__ _Float16 rows[4][4096];   // 32 KB
    __shared__ float u_s[4];
    int t = threadIdx.x, lane = t & 63, w = t >> 6;
    float2 acc[8];
#pragma unroll
    for (int s = 0; s < 8; ++s) acc[s] = make_float2(0.f, 0.f);

    for (int c = 0; c < 2; ++c) {
        if (c) __syncthreads();                    // prior phase-B reads done
        int row = blockIdx.x * 8 + c * 4 + w;
        const _Float16* Kr = Kh + (size_t)row * N_T;
        float dot = 0.f;
#pragma unroll
        for (int it = 0; it < 8; ++it) {
            int j0 = it * 512 + lane * 8;
            f16x8 kv = *(const f16x8*)(Kr + j0);
            float4 v0 = *(const float4*)(v + j0);
            float4 v1 = *(const float4*)(v + j0 + 4);
            *(f16x8*)(&rows[w][j0]) = kv;
            dot += (float)kv[0]*v0.x + (float)kv[1]*v0.y + (float)kv[2]*v0.z + (float)kv[3]*v0.w
                 + (float)kv[4]*v1.x + (float)kv[5]*v1.y + (float)kv[6]*v1.z + (float)kv[7]*v1.w;
        }
#pragma unroll
        for (int m = 32; m; m >>= 1) dot += __shfl_xor(dot, m);
        if (lane == 0) {
            float uv = (1.0f / N_S) / (dot + STAB);
            u_s[w] = uv;
            u_out[row] = uv;
        }
        __syncthreads();                           // rows + u_s visible
        // phase B: accumulate col partials (f16x2 per read, conflict-free stride-4B)
#pragma unroll
        for (int s = 0; s < 8; ++s) {
            int jj = t * 2 + s * 512;
#pragma unroll
            for (int r = 0; r < 4; ++r) {
                f16x2 kk = *(const f16x2*)(&rows[r][jj]);
                float uu = u_s[r];
                acc[s].x += uu * (float)kk[0];
                acc[s].y += uu * (float)kk[1];
            }
        }
    }
    float* pb = part + (size_t)blockIdx.x * N_T;
#pragma unroll
    for (int s = 0; s < 8; ++s)
        *(float2*)(pb + t * 2 + s * 512) = acc[s];
}

// ---------- reduce 512 partial vectors -> v ----------
__global__ __launch_bounds__(256) void k_vfin2(const float* __restrict__ part, float* __restrict__ v) {
    __shared__ float sums[256];
    int t = threadIdx.x;
    int jl = t & 15, c = t >> 4;                   // 16 cols x 16 chunks
    int j = blockIdx.x * 16 + jl;
    float acc = 0.f;
#pragma unroll 8
    for (int k = 0; k < 32; ++k)
        acc += part[(size_t)(c * 32 + k) * N_T + j];
    sums[t] = acc;
    __syncthreads();
    if (t < 16) {
        float s = 0.f;
#pragma unroll
        for (int c2 = 0; c2 < 16; ++c2) s += sums[c2 * 16 + t];
        v[blockIdx.x * 16 + t] = (1.0f / N_T) / (s + STAB);
    }
}

// ---------- coupling = u*Kh*v, fused loss ----------
__global__ __launch_bounds__(256) void k_final2(const _Float16* __restrict__ Kh, const float* __restrict__ Cd,
                                                const float* __restrict__ u, const float* __restrict__ v,
                                                float* __restrict__ W, double* __restrict__ lossd) {
    int t = threadIdx.x, row = blockIdx.x;
    float ui = u[row];
    float lacc = 0.f;
    const _Float16* Kr = Kh + (size_t)row * N_T;
    const float* Cr = Cd + (size_t)row * N_T;
    float* Wr = W + (size_t)row * N_T;
#pragma unroll
    for (int cc = 0; cc < 4; ++cc) {
        int j = (cc * 256 + t) * 4;
        f16x4 kk = *(const f16x4*)(Kr + j);
        float4 c4 = *(const float4*)(Cr + j);
        float4 v4 = *(const float4*)(v + j);
        float4 w4;
        w4.x = ui * (float)kk[0] * v4.x;
        w4.y = ui * (float)kk[1] * v4.y;
        w4.z = ui * (float)kk[2] * v4.z;
        w4.w = ui * (float)kk[3] * v4.w;
        *(float4*)(Wr + j) = w4;
        lacc += w4.x*c4.x + w4.y*c4.y + w4.z*c4.z + w4.w*c4.w;
    }
#pragma unroll
    for (int m = 32; m; m >>= 1) lacc += __shfl_xor(lacc, m);
    __shared__ float wsum[4];
    int lane = t & 63, wave = t >> 6;
    if (lane == 0) wsum[wave] = lacc;
    __syncthreads();
    if (t == 0) atomicAdd(lossd, (double)(wsum[0] + wsum[1] + wsum[2] + wsum[3]));
}

__global__ void k_loss(const double* __restrict__ lossd, float* __restrict__ out0) {
    *out0 = (float)(*lossd / ((double)N_S * (double)N_T));
}

// ================= fallback (round-1 proven) kernels =================
__global__ __launch_bounds__(256) void k_rowmv(const float* __restrict__ Kd,
                                               const float* __restrict__ v, float* __restrict__ u) {
    __shared__ float vl[4096];
    int t = threadIdx.x;
#pragma unroll
    for (int c = 0; c < 16; ++c) vl[c * 256 + t] = v[c * 256 + t];
    __syncthreads();
    int lane = t & 63, wave = t >> 6;
    int row = blockIdx.x * 4 + wave;
    const float* Kr = Kd + (size_t)row * N_T;
    float dot = 0.f;
#pragma unroll 8
    for (int c = 0; c < 64; ++c) {
        int j = c * 64 + lane;
        dot += Kr[j] * vl[j];
    }
#pragma unroll
    for (int m = 32; m; m >>= 1) dot += __shfl_xor(dot, m);
    if (lane == 0) u[row] = (1.0f / N_S) / (dot + STAB);
}

__global__ __launch_bounds__(256) void k_colmv(const float* __restrict__ Kd,
                                               const float* __restrict__ u, float* __restrict__ vacc) {
    __shared__ float ul[64];
    int t = threadIdx.x;
    int rc = blockIdx.y;
    if (t < 64) ul[t] = u[rc * 64 + t];
    __syncthreads();
    int j = blockIdx.x * 256 + t;
    const float* Kp = Kd + (size_t)(rc * 64) * N_T + j;
    float acc = 0.f;
#pragma unroll 8
    for (int r = 0; r < 64; ++r) acc += Kp[(size_t)r * N_T] * ul[r];
    atomicAdd(&vacc[j], acc);
}

__global__ void k_vfin(float* v, float* vacc) {
    int j = blockIdx.x * 256 + threadIdx.x;
    v[j] = (1.0f / N_T) / (vacc[j] + STAB);
    vacc[j] = 0.f;
}

__global__ __launch_bounds__(256) void k_final(float* __restrict__ Kd, const float* __restrict__ Cd,
                                               const float* __restrict__ u, const float* __restrict__ v,
                                               double* __restrict__ lossd) {
    int t = threadIdx.x;
    int row = blockIdx.x;
    float ui = u[row];
    float lacc = 0.f;
#pragma unroll 4
    for (int c = 0; c < 16; ++c) {
        int j = c * 256 + t;
        size_t idx = (size_t)row * N_T + j;
        float w = ui * Kd[idx] * v[j];
        Kd[idx] = w;
        lacc += w * Cd[idx];
    }
#pragma unroll
    for (int m = 32; m; m >>= 1) lacc += __shfl_xor(lacc, m);
    __shared__ float wsum[4];
    int lane = t & 63, wave = t >> 6;
    if (lane == 0) wsum[wave] = lacc;
    __syncthreads();
    if (t == 0) atomicAdd(lossd, (double)(wsum[0] + wsum[1] + wsum[2] + wsum[3]));
}

// =====================================================================
extern "C" void kernel_launch(void* const* d_in, const int* in_sizes, int n_in,
                              void* d_out, int out_size, void* d_ws, size_t ws_size,
                              hipStream_t stream) {
    const float* S = (const float*)d_in[0];
    const float* T = (const float*)d_in[1];
    float* out = (float*)d_out;
    float* outCoup = out + 1;
    float* outC = out + 1 + (size_t)N_S * N_T;

    const size_t KH_BYTES = (size_t)N_S * N_T * 2;          // 32 MB
    const size_t PART_BYTES = (size_t)512 * N_T * 4;        // 8 MB
    const size_t need = KH_BYTES + PART_BYTES + 4 * 16384 + 16;

    if (ws_size >= need) {
        _Float16* kh = (_Float16*)d_ws;
        float* part = (float*)((char*)d_ws + KH_BYTES);
        float* ns = (float*)((char*)d_ws + KH_BYTES + PART_BYTES);
        float* nt = ns + 4096;
        float* u  = nt + 4096;
        float* v  = u + 4096;
        double* lossd = (double*)(v + 4096);

        k_norms<<<2048, 256, 0, stream>>>((const float4*)S, (const float4*)T, ns, nt);
        k_init<<<16, 256, 0, stream>>>(v, part, lossd);
        k_gemm<1><<<dim3(32, 32), 256, 0, stream>>>(S, T, ns, nt, nullptr, kh, outC);
        for (int it = 0; it < 10; ++it) {
            k_sink<<<512, 256, 0, stream>>>(kh, v, u, part);
            k_vfin2<<<256, 256, 0, stream>>>(part, v);
        }
        k_final2<<<4096, 256, 0, stream>>>(kh, outC, u, v, outCoup, lossd);
        k_loss<<<1, 1, 0, stream>>>(lossd, out);
    } else {
        // round-1 proven fallback: fp32 K staged in coupling slot
        float* outK = outCoup;
        float* ws   = (float*)d_ws;
        float* ns   = ws;
        float* nt   = ws + 4096;
        float* u    = ws + 8192;
        float* v    = ws + 12288;
        float* vacc = ws + 16384;
        double* lossd = (double*)(ws + 20480);

        k_norms<<<2048, 256, 0, stream>>>((const float4*)S, (const float4*)T, ns, nt);
        k_init<<<16, 256, 0, stream>>>(v, vacc, lossd);
        k_gemm<0><<<dim3(32, 32), 256, 0, stream>>>(S, T, ns, nt, outK, nullptr, outC);
        for (int it = 0; it < 10; ++it) {
            k_rowmv<<<1024, 256, 0, stream>>>(outK, v, u);
            k_colmv<<<dim3(16, 64), 256, 0, stream>>>(outK, u, vacc);
            k_vfin<<<16, 256, 0, stream>>>(v, vacc);
        }
        k_final<<<4096, 256, 0, stream>>>(outK, outC, u, v, lossd);
        k_loss<<<1, 1, 0, stream>>>(lossd, out);
    }
}